// Round 9
// baseline (363.974 us; speedup 1.0000x reference)
//
#include <hip/hip_runtime.h>
#include <cstddef>

// B=16, h=8, Ch=32, H=W=56, N=3136
// out[b][n][hh*32+ch] = q[b][hh][n][ch] * dwconv(v)[b][hh][n][ch]
//
// R14: write-granule retest, spill-free. R13 was CONFOUNDED: VGPR hit the
// 256 cap and scratch spills added +25MB FETCH / +57MB WRITE. This round
// tests the same hypothesis (prior rounds' 128B-at-1KB-stride out stores
// => ~random 128B write granules at HBM => ~20% page efficiency binds the
// kernel at ~2TB/s) with a lean structure:
//  - block = 512 thr / 8 waves, one (b,y) row, ONE head per wave (single
//    pass, one K-template per wave -> no cross-pass register pressure).
//  - q-multiply moved to the store phase (conv body never touches q).
//  - wave-private staging buffer = R6's proven 64-slot layout (4-px zero
//    pads both sides, no edge masks).
//  - store phase: all 8 head slices assembled in a 57KB LDS row buffer,
//    written as fully CONTIGUOUS 1-KB bursts (the experiment).
// Tap balance across waves: 9/9/25/25/25/49/49/49 (block ends at K7 waves;
// acceptable -- purpose is the write pattern, not the last 10%).

#define BH 16
#define NH 8
#define CH 32
#define HW 56
#define NN (HW*HW)
#define ROWB (HW*CH*4)          // 7168 B per image row
#define WBF 2048                // wave-private buf: 64 px slots * 32 ch
#define OUTROWF 264             // out-LDS floats per px (256 + 8 pad)
// weight LDS layout [tap][ch]: w3 @0 (stride 64), w5 @576 (stride 96),
// w7 @2976 (stride 96); total 7680 floats.
#define W3O 0
#define W5O 576
#define W7O 2976
#define WTOT 7680

typedef float f32x4 __attribute__((ext_vector_type(4)));
typedef unsigned int u32x4 __attribute__((ext_vector_type(4)));

__device__ __forceinline__ f32x4 bload(__amdgpu_buffer_rsrc_t rs, int voff) {
    u32x4 u = __builtin_amdgcn_raw_buffer_load_b128(rs, voff, 0, 0);
    f32x4 f; __builtin_memcpy(&f, &u, 16); return f;
}

// One head, one output row y: rolling conv (2-deep row pipeline, stage row
// into wave-private LDS, window from LDS, FMA), park raw conv into outL.
template<int K, int CT>
__device__ __forceinline__ void head_row(
    const float* __restrict__ v,
    const float* __restrict__ whead,   // w_lds + tensor off + cbase
    const float* __restrict__ bias_c,  // bias tensor + cbase
    float* __restrict__ outL, float* __restrict__ wb,
    size_t plane, int hh, int y, int lane)
{
    constexpr int P  = K / 2;
    constexpr int NR = 7 + K - 1;
    const int xseg = lane >> 3;         // 8 x-strips of 7 px
    const int chq  = lane & 7;          // 8 ch-quads
    const int x0   = xseg * 7;
    const int ch   = chq * 4;

    const float* vb  = v + plane;
    const float* whc = whead + ch;      // w4 = whc[tap*CT]

    const f32x4 bias4 = *(const f32x4*)(bias_c + ch);
    f32x4 acc[7];
#pragma unroll
    for (int i = 0; i < 7; ++i) acc[i] = bias4;

    // 2-deep pipelined dy loop (unrolled -> ld indices constant).
    // OOB rows: num_records=0 -> loads return 0 = y zero-padding (R2-R4).
    f32x4 ld[2][7];
    {
        const int yy = y - P;
        const bool ok = (unsigned)yy < (unsigned)HW;
        __amdgpu_buffer_rsrc_t rs0 = __builtin_amdgcn_make_buffer_rsrc(
            (void*)(vb + (ptrdiff_t)yy * (HW * CH)), (short)0, ok ? ROWB : 0, 0x00020000);
#pragma unroll
        for (int k = 0; k < 7; ++k) ld[0][k] = bload(rs0, k * 1024 + lane * 16);
    }
#pragma unroll
    for (int dy = 0; dy < K; ++dy) {
        if (dy + 1 < K) {
            const int yy = y + dy + 1 - P;
            const bool ok = (unsigned)yy < (unsigned)HW;
            __amdgpu_buffer_rsrc_t rs = __builtin_amdgcn_make_buffer_rsrc(
                (void*)(vb + (ptrdiff_t)yy * (HW * CH)), (short)0, ok ? ROWB : 0, 0x00020000);
#pragma unroll
            for (int k = 0; k < 7; ++k) ld[(dy + 1) & 1][k] = bload(rs, k * 1024 + lane * 16);
        }
        // stage current row into wave-private buffer, slots 4..59
        // (slots 0..3 / 60..63 are permanent zero x-pads; DS ops are
        // in-order per wave, so WAR across dy iterations is safe).
#pragma unroll
        for (int k = 0; k < 7; ++k)
            *(f32x4*)(wb + k * 256 + 128 + lane * 4) = ld[dy & 1][k];

        // window from LDS: slot = px + 4; covers px -3..58 for K=7.
        const float* rb = wb + (size_t)(x0 - P + 4) * CH + ch;
        f32x4 r[NR];
#pragma unroll
        for (int j = 0; j < NR; ++j)
            r[j] = *(const f32x4*)(rb + j * CH);

#pragma unroll
        for (int dx = 0; dx < K; ++dx) {
            const f32x4 w4 = *(const f32x4*)(whc + (dy * K + dx) * CT);
#pragma unroll
            for (int i = 0; i < 7; ++i)
                acc[i] += r[i + dx] * w4;
        }
    }

    // Park raw conv into out-LDS row [px][hh*32+ch] (2-way bank = free).
#pragma unroll
    for (int i = 0; i < 7; ++i)
        *(f32x4*)(outL + (size_t)(x0 + i) * OUTROWF + hh * CH + ch) = acc[i];
}

__global__ __launch_bounds__(512, 1)   // 155.4 KB LDS -> 1 block/CU
void clusterformer_fused(const float* __restrict__ q, const float* __restrict__ v,
                         const float* __restrict__ w3, const float* __restrict__ b3,
                         const float* __restrict__ w5, const float* __restrict__ b5,
                         const float* __restrict__ w7, const float* __restrict__ b7,
                         float* __restrict__ out)
{
    __shared__ __align__(16) float w_lds[WTOT];          // 30720 B
    __shared__ __align__(16) float bufs[8 * WBF];        // 65536 B
    __shared__ __align__(16) float outL[HW * OUTROWF];   // 59136 B

    const int t    = threadIdx.x;
    const int wid  = t >> 6;            // 0..7 = head
    const int lane = t & 63;

    // bid -> (b, y): b&7 = XCD (v/q planes XCD-local); same-b blocks are
    // consecutive slots -> neighbor y-blocks share halo rows in L2.
    const int bid  = blockIdx.x;       // 0..895
    const int xcd  = bid & 7;
    const int slot = bid >> 3;         // 0..111
    const int b_hi = (slot >= 56) ? 1 : 0;
    const int y    = slot - b_hi * 56;
    const int b    = (b_hi << 3) | xcd;

    // Stage all weights, layout [tap][ch] per tensor.
    for (int i = t; i < WTOT; i += 512) {
        float val;
        if (i < W5O) {                       // w3: 9 taps x 64 ch
            const int tap = i >> 6, c = i & 63;
            val = w3[c * 9 + tap];
        } else if (i < W7O) {                // w5: 25 taps x 96 ch
            const int j = i - W5O, tap = j / 96, c = j % 96;
            val = w5[c * 25 + tap];
        } else {                             // w7: 49 taps x 96 ch
            const int j = i - W7O, tap = j / 96, c = j % 96;
            val = w7[c * 49 + tap];
        }
        w_lds[i] = val;
    }

    // Permanent zero x-pads in the wave-private buffer: slots 0..3, 60..63.
    float* wb = bufs + wid * WBF;
    {
        f32x4 z = {0.f, 0.f, 0.f, 0.f};
        const int half = lane & 31;
        float* zb = (lane < 32) ? wb : (wb + 60 * CH);
        *(f32x4*)(zb + half * 4) = z;
    }
    __syncthreads();                    // weights + pads ready

    // One head per wave (single K-template instantiation per wave).
    const size_t plane = ((size_t)b * NH + wid) * (size_t)NN * CH;
    if (wid < 2)
        head_row<3, 64>(v, w_lds + W3O + wid * 32,        b3 + wid * 32,        outL, wb, plane, wid, y, lane);
    else if (wid < 5)
        head_row<5, 96>(v, w_lds + W5O + (wid * 32 - 64), b5 + (wid * 32 - 64), outL, wb, plane, wid, y, lane);
    else
        head_row<7, 96>(v, w_lds + W7O + (wid * 32 - 160), b7 + (wid * 32 - 160), outL, wb, plane, wid, y, lane);

    __syncthreads();                    // all 8 head slices parked

    // Store phase: q-multiply + fully CONTIGUOUS 1-KB record stores.
    // Store lane mapping: hh = lane>>3, ch = (lane&7)*4 -> q reads are
    // 8 x 128-B segments per instruction (as prior epilogues).
    const int sh = lane >> 3;
    const int sc = (lane & 7) * 4;
    const float* qh = q + (((size_t)b * NH + sh) * (size_t)NN + (size_t)y * HW) * CH + sc;
    float* orow = out + ((size_t)b * NN + (size_t)y * HW) * (NH * CH);

    f32x4 q4[7];
#pragma unroll
    for (int m = 0; m < 7; ++m) {
        const int px = m * 8 + wid;
        q4[m] = *(const f32x4*)(qh + (size_t)px * CH);
    }
#pragma unroll
    for (int m = 0; m < 7; ++m) {
        const int px = m * 8 + wid;
        const f32x4 c4 = *(const f32x4*)(outL + (size_t)px * OUTROWF + lane * 4);
        *(f32x4*)(orow + (size_t)px * (NH * CH) + lane * 4) = c4 * q4[m];
    }
}

extern "C" void kernel_launch(void* const* d_in, const int* in_sizes, int n_in,
                              void* d_out, int out_size, void* d_ws, size_t ws_size,
                              hipStream_t stream) {
    const float* q  = (const float*)d_in[0];
    const float* v  = (const float*)d_in[1];
    const float* w3 = (const float*)d_in[2];
    const float* b3 = (const float*)d_in[3];
    const float* w5 = (const float*)d_in[4];
    const float* b5 = (const float*)d_in[5];
    const float* w7 = (const float*)d_in[6];
    const float* b7 = (const float*)d_in[7];
    float* out = (float*)d_out;

    const int grid = BH * HW;          // 896 blocks of 512 threads
    clusterformer_fused<<<grid, 512, 0, stream>>>(q, v, w3, b3, w5, b5, w7, b7, out);
}

// Round 10
// 253.112 us; speedup vs baseline: 1.4380x; 1.4380x over previous
//
#include <hip/hip_runtime.h>
#include <cstddef>

// B=16, h=8, Ch=32, H=W=56, N=3136
// out[b][n][hh*32+ch] = q[b][hh][n][ch] * dwconv(v)[b][hh][n][ch]
//
// R15: write-granule test, attempt #3 (R13: spilled at 256 VGPR; R14:
// compiler capped 128 VGPR at 512 threads -> massive scratch). Hypothesis
// under test: prior rounds' out stores (128-B head-slices at 1-KB stride,
// merged across blocks/XCDs only at HBM) present ~128-B write granules to
// DRAM (~20% page efficiency) and bind the kernel at ~2 TB/s effective.
// This round: block = 256 thr / 4 waves = one (b,y) row x all 8 heads
// (wave runs head pair (0,5)(1,6)(2,7)(3,4), tap-balanced 58/58/74/50);
// conv slices parked in a 57-KB LDS row buffer; store phase writes fully
// CONTIGUOUS 1-KB records (57 KB sequential per block).
// Register hygiene (the R13/R14 lesson): q-multiply moved to store phase
// (conv body never holds qf), 64-slot wave buffer, 2-deep row pipeline
// only (peak live ~160), launch_bounds(256,1) (R9 proved 248 VGPR clean).
// Clean-run criteria: VGPR<=230, WRITE=50176 KB exactly, FETCH 51-56 MB.

#define BH 16
#define NH 8
#define CH 32
#define HW 56
#define NN (HW*HW)
#define ROWB (HW*CH*4)          // 7168 B per image row
#define WBF 2048                // wave-private buf: 64 px slots * 32 ch
#define OUTROWF 264             // out-LDS floats per px (256 + 8 pad)
// weight LDS layout [tap][ch]: w3 @0 (stride 64), w5 @576 (stride 96),
// w7 @2976 (stride 96); total 7680 floats.
#define W3O 0
#define W5O 576
#define W7O 2976
#define WTOT 7680

typedef float f32x4 __attribute__((ext_vector_type(4)));
typedef unsigned int u32x4 __attribute__((ext_vector_type(4)));

__device__ __forceinline__ f32x4 bload(__amdgpu_buffer_rsrc_t rs, int voff) {
    u32x4 u = __builtin_amdgcn_raw_buffer_load_b128(rs, voff, 0, 0);
    f32x4 f; __builtin_memcpy(&f, &u, 16); return f;
}

// One head, one output row y: rolling conv (2-deep row pipeline, stage row
// into wave-private LDS, window from LDS, FMA), park RAW conv into outL.
// No q access here (register hygiene).
template<int K, int CT>
__device__ __forceinline__ void head_row(
    const float* __restrict__ v,
    const float* __restrict__ whc0,    // w_lds + tensor off + head cbase
    const float* __restrict__ bias_c,  // bias tensor + head cbase
    float* __restrict__ outL, float* __restrict__ wb,
    size_t plane, int hh, int y, int lane)
{
    constexpr int P  = K / 2;
    constexpr int NR = 7 + K - 1;
    const int xseg = lane >> 3;         // 8 x-strips of 7 px
    const int chq  = lane & 7;          // 8 ch-quads
    const int x0   = xseg * 7;
    const int ch   = chq * 4;

    const float* vb  = v + plane;
    const float* whc = whc0 + ch;       // w4 = whc[tap*CT]

    const f32x4 bias4 = *(const f32x4*)(bias_c + ch);
    f32x4 acc[7];
#pragma unroll
    for (int i = 0; i < 7; ++i) acc[i] = bias4;

    // 2-deep pipelined dy loop (unrolled -> ld indices constant).
    // OOB rows: num_records=0 -> loads return 0 = y zero-padding (R2-R4).
    f32x4 ld[2][7];
    {
        const int yy = y - P;
        const bool ok = (unsigned)yy < (unsigned)HW;
        __amdgpu_buffer_rsrc_t rs0 = __builtin_amdgcn_make_buffer_rsrc(
            (void*)(vb + (ptrdiff_t)yy * (HW * CH)), (short)0, ok ? ROWB : 0, 0x00020000);
#pragma unroll
        for (int k = 0; k < 7; ++k) ld[0][k] = bload(rs0, k * 1024 + lane * 16);
    }
#pragma unroll
    for (int dy = 0; dy < K; ++dy) {
        if (dy + 1 < K) {
            const int yy = y + dy + 1 - P;
            const bool ok = (unsigned)yy < (unsigned)HW;
            __amdgpu_buffer_rsrc_t rs = __builtin_amdgcn_make_buffer_rsrc(
                (void*)(vb + (ptrdiff_t)yy * (HW * CH)), (short)0, ok ? ROWB : 0, 0x00020000);
#pragma unroll
            for (int k = 0; k < 7; ++k) ld[(dy + 1) & 1][k] = bload(rs, k * 1024 + lane * 16);
        }
        // stage current row into wave-private buffer, slots 4..59
        // (slots 0..3 / 60..63 are permanent zero x-pads; DS ops are
        // in-order per wave, so WAR across dy iterations is safe).
#pragma unroll
        for (int k = 0; k < 7; ++k)
            *(f32x4*)(wb + k * 256 + 128 + lane * 4) = ld[dy & 1][k];

        // window from LDS: slot = px + 4; covers px -3..58 for K=7.
        const float* rb = wb + (size_t)(x0 - P + 4) * CH + ch;
        f32x4 r[NR];
#pragma unroll
        for (int j = 0; j < NR; ++j)
            r[j] = *(const f32x4*)(rb + j * CH);

#pragma unroll
        for (int dx = 0; dx < K; ++dx) {
            const f32x4 w4 = *(const f32x4*)(whc + (dy * K + dx) * CT);
#pragma unroll
            for (int i = 0; i < 7; ++i)
                acc[i] += r[i + dx] * w4;
        }
    }

    // Park raw conv into out-LDS row [px][hh*32+ch]
    // (stride 1056 B => bank rotation 8/px; worst 2-way conflict = free).
#pragma unroll
    for (int i = 0; i < 7; ++i)
        *(f32x4*)(outL + (size_t)(x0 + i) * OUTROWF + hh * CH + ch) = acc[i];
}

__device__ __forceinline__ void do_head(
    const float* q_unused, const float* v,
    const float* w_lds,
    const float* b3, const float* b5, const float* b7,
    float* outL, float* wb, int b, int hh, int y, int lane)
{
    const size_t plane = ((size_t)b * NH + hh) * (size_t)NN * CH;
    if (hh < 2)
        head_row<3, 64>(v, w_lds + W3O + hh * 32,         b3 + hh * 32,         outL, wb, plane, hh, y, lane);
    else if (hh < 5)
        head_row<5, 96>(v, w_lds + W5O + (hh * 32 - 64),  b5 + (hh * 32 - 64),  outL, wb, plane, hh, y, lane);
    else
        head_row<7, 96>(v, w_lds + W7O + (hh * 32 - 160), b7 + (hh * 32 - 160), outL, wb, plane, hh, y, lane);
}

__global__ __launch_bounds__(256, 1)   // 119.7 KB LDS -> 1 block/CU
void clusterformer_fused(const float* __restrict__ q, const float* __restrict__ v,
                         const float* __restrict__ w3, const float* __restrict__ b3,
                         const float* __restrict__ w5, const float* __restrict__ b5,
                         const float* __restrict__ w7, const float* __restrict__ b7,
                         float* __restrict__ out)
{
    __shared__ __align__(16) float w_lds[WTOT];          // 30720 B
    __shared__ __align__(16) float bufs[4 * WBF];        // 32768 B
    __shared__ __align__(16) float outL[HW * OUTROWF];   // 59136 B

    const int t    = threadIdx.x;
    const int wid  = t >> 6;            // 0..3
    const int lane = t & 63;

    // bid -> (b, y): b&7 = XCD (v/q planes XCD-local); same-b blocks are
    // consecutive slots -> neighbor y-blocks share halo rows in L2.
    const int bid  = blockIdx.x;       // 0..895
    const int xcd  = bid & 7;
    const int slot = bid >> 3;         // 0..111
    const int b_hi = (slot >= 56) ? 1 : 0;
    const int y    = slot - b_hi * 56;
    const int b    = (b_hi << 3) | xcd;

    // Stage all weights, layout [tap][ch] per tensor.
    for (int i = t; i < WTOT; i += 256) {
        float val;
        if (i < W5O) {                       // w3: 9 taps x 64 ch
            const int tap = i >> 6, c = i & 63;
            val = w3[c * 9 + tap];
        } else if (i < W7O) {                // w5: 25 taps x 96 ch
            const int j = i - W5O, tap = j / 96, c = j % 96;
            val = w5[c * 25 + tap];
        } else {                             // w7: 49 taps x 96 ch
            const int j = i - W7O, tap = j / 96, c = j % 96;
            val = w7[c * 49 + tap];
        }
        w_lds[i] = val;
    }

    // Permanent zero x-pads in the wave-private buffer: slots 0..3, 60..63.
    float* wb = bufs + wid * WBF;
    {
        f32x4 z = {0.f, 0.f, 0.f, 0.f};
        const int half = lane & 31;
        float* zb = (lane < 32) ? wb : (wb + 60 * CH);
        *(f32x4*)(zb + half * 4) = z;
    }
    __syncthreads();                    // weights + pads ready

    // Wave runs two heads sequentially: pairs (0,5)(1,6)(2,7)(3,4)
    // (tap cost 58/58/74/50). Wave-private wb => no barrier between them.
    do_head(q, v, w_lds, b3, b5, b7, outL, wb, b, wid, y, lane);
    const int h2tab[4] = {5, 6, 7, 4};
    do_head(q, v, w_lds, b3, b5, b7, outL, wb, b, h2tab[wid], y, lane);

    __syncthreads();                    // all 8 head slices parked

    // Store phase (THE EXPERIMENT): q-multiply + fully CONTIGUOUS 1-KB
    // record stores; block writes 57,344 B sequential.
    // Lane mapping: sh = lane>>3 (head), sc = (lane&7)*4 (ch quad) ->
    // q reads are 8 x 128-B segments per instr (same as prior epilogues).
    const int sh = lane >> 3;
    const int sc = (lane & 7) * 4;
    const float* qh = q + (((size_t)b * NH + sh) * (size_t)NN + (size_t)y * HW) * CH + sc;
    float* orow = out + ((size_t)b * NN + (size_t)y * HW) * (NH * CH);

    f32x4 q4[14];
#pragma unroll
    for (int m = 0; m < 14; ++m) {
        const int px = m * 4 + wid;
        q4[m] = *(const f32x4*)(qh + (size_t)px * CH);
    }
#pragma unroll
    for (int m = 0; m < 14; ++m) {
        const int px = m * 4 + wid;
        const f32x4 c4 = *(const f32x4*)(outL + (size_t)px * OUTROWF + lane * 4);
        *(f32x4*)(orow + (size_t)px * (NH * CH) + lane * 4) = c4 * q4[m];
    }
}

extern "C" void kernel_launch(void* const* d_in, const int* in_sizes, int n_in,
                              void* d_out, int out_size, void* d_ws, size_t ws_size,
                              hipStream_t stream) {
    const float* q  = (const float*)d_in[0];
    const float* v  = (const float*)d_in[1];
    const float* w3 = (const float*)d_in[2];
    const float* b3 = (const float*)d_in[3];
    const float* w5 = (const float*)d_in[4];
    const float* b5 = (const float*)d_in[5];
    const float* w7 = (const float*)d_in[6];
    const float* b7 = (const float*)d_in[7];
    float* out = (float*)d_out;

    const int grid = BH * HW;          // 896 blocks of 256 threads
    clusterformer_fused<<<grid, 256, 0, stream>>>(q, v, w3, b3, w5, b5, w7, b7, out);
}

// Round 11
// 179.756 us; speedup vs baseline: 2.0248x; 1.4081x over previous
//
#include <hip/hip_runtime.h>
#include <cstddef>

// B=16, h=8, Ch=32, H=W=56, N=3136
// out[b][n][hh*32+ch] = q[b][hh][n][ch] * dwconv(v)[b][hh][n][ch]
//
// R16: write-granule test, attempt #4. R13/R14/R15 all spill-confounded
// (VGPR cap / runtime-K inlining merge). Hypothesis: clean rounds' out
// stores (128-B head-slices at 1-KB stride) present ~128-B write granules
// to DRAM (~20% HBM page efficiency) and bind the kernel at ~2 TB/s.
// This round: block = 256 thr / 4 waves = one (b,y) row x all 8 heads;
// conv parked raw in 57-KB LDS row buffer; store phase writes fully
// CONTIGUOUS 1-KB records (57 KB sequential per block).
// Spill fixes vs R15:
//  - STATIC head dispatch: switch(wid) with 8 concrete head_row<K,CT>
//    instantiations (2 per branch, compile-time hh) - no runtime-K merge.
//  - runtime dy loop, single-buffer staging (R8/R9-proven): per-branch
//    body ~3KB (icache-safe), peak live ~130 VGPR.
//  - store epilogue chunked (q4[7] per chunk, not 14).
// Clean-run criteria: VGPR<=190, WRITE=50176 KB exactly, FETCH 52-60 MB.
// Outcome (clean): granule true => ~36-44us; false => flat 52-60us.

#define BH 16
#define NH 8
#define CH 32
#define HW 56
#define NN (HW*HW)
#define ROWB (HW*CH*4)          // 7168 B per image row
#define WBF 2048                // wave-private buf: 64 px slots * 32 ch
#define OUTROWF 264             // out-LDS floats per px (256 + 8 pad)
// weight LDS layout [tap][ch]: w3 @0 (stride 64), w5 @576 (stride 96),
// w7 @2976 (stride 96); total 7680 floats.
#define W3O 0
#define W5O 576
#define W7O 2976
#define WTOT 7680

typedef float f32x4 __attribute__((ext_vector_type(4)));
typedef unsigned int u32x4 __attribute__((ext_vector_type(4)));

__device__ __forceinline__ f32x4 bload(__amdgpu_buffer_rsrc_t rs, int voff) {
    u32x4 u = __builtin_amdgcn_raw_buffer_load_b128(rs, voff, 0, 0);
    f32x4 f; __builtin_memcpy(&f, &u, 16); return f;
}

// One head, one output row y. Runtime dy loop: stage row dy into the
// wave-private buffer (single-buffered; DS ops are in-order per wave so
// WAR across iterations is safe), window from LDS, FMA into acc, then
// park RAW conv into outL. No q access (register hygiene).
template<int K, int CT>
__device__ __forceinline__ void head_row(
    const float* __restrict__ v,
    const float* __restrict__ whc0,    // w_lds + tensor off + head cbase
    const float* __restrict__ bias_c,  // bias tensor + head cbase
    float* __restrict__ outL, float* __restrict__ wb,
    size_t plane, int hh, int y, int lane)
{
    constexpr int P  = K / 2;
    constexpr int NR = 7 + K - 1;
    const int xseg = lane >> 3;         // 8 x-strips of 7 px
    const int chq  = lane & 7;          // 8 ch-quads
    const int x0   = xseg * 7;
    const int ch   = chq * 4;

    const float* vb  = v + plane;
    const float* whc = whc0 + ch;       // w4 = whc[(dy*K+dx)*CT]

    const f32x4 bias4 = *(const f32x4*)(bias_c + ch);
    f32x4 acc[7];
#pragma unroll
    for (int i = 0; i < 7; ++i) acc[i] = bias4;

    // OOB rows: num_records=0 -> loads return 0 = y zero-padding (R2-R4).
    for (int dy = 0; dy < K; ++dy) {    // RUNTIME loop (icache + regs)
        const int yy = y + dy - P;
        const bool ok = (unsigned)yy < (unsigned)HW;
        __amdgpu_buffer_rsrc_t rs = __builtin_amdgcn_make_buffer_rsrc(
            (void*)(vb + (ptrdiff_t)yy * (HW * CH)), (short)0, ok ? ROWB : 0, 0x00020000);
        f32x4 ld[7];
#pragma unroll
        for (int k = 0; k < 7; ++k) ld[k] = bload(rs, k * 1024 + lane * 16);
        // stage into slots 4..59 (slots 0..3 / 60..63 = permanent zero pads)
#pragma unroll
        for (int k = 0; k < 7; ++k)
            *(f32x4*)(wb + k * 256 + 128 + lane * 4) = ld[k];

        // window from LDS: slot = px + 4; covers px -3..58 for K=7.
        const float* rb = wb + (size_t)(x0 - P + 4) * CH + ch;
        f32x4 r[NR];
#pragma unroll
        for (int j = 0; j < NR; ++j)
            r[j] = *(const f32x4*)(rb + j * CH);

        const float* wrow = whc + dy * K * CT;
#pragma unroll
        for (int dx = 0; dx < K; ++dx) {
            const f32x4 w4 = *(const f32x4*)(wrow + dx * CT);
#pragma unroll
            for (int i = 0; i < 7; ++i)
                acc[i] += r[i + dx] * w4;
        }
    }

    // Park raw conv into out-LDS row [px][hh*32+ch] (2-way bank = free).
#pragma unroll
    for (int i = 0; i < 7; ++i)
        *(f32x4*)(outL + (size_t)(x0 + i) * OUTROWF + hh * CH + ch) = acc[i];
}

__global__ __launch_bounds__(256, 1)   // 119.7 KB LDS -> 1 block/CU
void clusterformer_fused(const float* __restrict__ q, const float* __restrict__ v,
                         const float* __restrict__ w3, const float* __restrict__ b3,
                         const float* __restrict__ w5, const float* __restrict__ b5,
                         const float* __restrict__ w7, const float* __restrict__ b7,
                         float* __restrict__ out)
{
    __shared__ __align__(16) float w_lds[WTOT];          // 30720 B
    __shared__ __align__(16) float bufs[4 * WBF];        // 32768 B
    __shared__ __align__(16) float outL[HW * OUTROWF];   // 59136 B

    const int t    = threadIdx.x;
    const int wid  = t >> 6;            // 0..3
    const int lane = t & 63;

    // bid -> (b, y): b&7 = XCD (v/q planes XCD-local); same-b blocks are
    // consecutive slots -> neighbor y-blocks share halo rows in L2.
    const int bid  = blockIdx.x;       // 0..895
    const int xcd  = bid & 7;
    const int slot = bid >> 3;         // 0..111
    const int b_hi = (slot >= 56) ? 1 : 0;
    const int y    = slot - b_hi * 56;
    const int b    = (b_hi << 3) | xcd;

    // Stage all weights, layout [tap][ch] per tensor.
    for (int i = t; i < WTOT; i += 256) {
        float val;
        if (i < W5O) {                       // w3: 9 taps x 64 ch
            const int tap = i >> 6, c = i & 63;
            val = w3[c * 9 + tap];
        } else if (i < W7O) {                // w5: 25 taps x 96 ch
            const int j = i - W5O, tap = j / 96, c = j % 96;
            val = w5[c * 25 + tap];
        } else {                             // w7: 49 taps x 96 ch
            const int j = i - W7O, tap = j / 96, c = j % 96;
            val = w7[c * 49 + tap];
        }
        w_lds[i] = val;
    }

    // Permanent zero x-pads in the wave-private buffer: slots 0..3, 60..63.
    float* wb = bufs + wid * WBF;
    {
        f32x4 z = {0.f, 0.f, 0.f, 0.f};
        const int half = lane & 31;
        float* zb = (lane < 32) ? wb : (wb + 60 * CH);
        *(f32x4*)(zb + half * 4) = z;
    }
    __syncthreads();                    // weights + pads ready

    // STATIC head-pair dispatch: (0,5)(1,6)(2,7)(3,4), taps 58/58/74/50.
    // Each branch: exactly two concrete template instantiations,
    // compile-time hh/cbase. Wave-private wb reused sequentially (safe).
    const size_t pb = (size_t)b * NH * (size_t)NN * CH;
    const size_t ps = (size_t)NN * CH;  // plane stride per head
    switch (wid) {
    case 0:
        head_row<3, 64>(v, w_lds + W3O +  0, b3 +  0, outL, wb, pb + 0 * ps, 0, y, lane);
        head_row<7, 96>(v, w_lds + W7O +  0, b7 +  0, outL, wb, pb + 5 * ps, 5, y, lane);
        break;
    case 1:
        head_row<3, 64>(v, w_lds + W3O + 32, b3 + 32, outL, wb, pb + 1 * ps, 1, y, lane);
        head_row<7, 96>(v, w_lds + W7O + 32, b7 + 32, outL, wb, pb + 6 * ps, 6, y, lane);
        break;
    case 2:
        head_row<5, 96>(v, w_lds + W5O +  0, b5 +  0, outL, wb, pb + 2 * ps, 2, y, lane);
        head_row<7, 96>(v, w_lds + W7O + 64, b7 + 64, outL, wb, pb + 7 * ps, 7, y, lane);
        break;
    default:
        head_row<5, 96>(v, w_lds + W5O + 32, b5 + 32, outL, wb, pb + 3 * ps, 3, y, lane);
        head_row<5, 96>(v, w_lds + W5O + 64, b5 + 64, outL, wb, pb + 4 * ps, 4, y, lane);
        break;
    }
    __syncthreads();                    // all 8 head slices parked

    // Store phase (THE EXPERIMENT): q-multiply + fully CONTIGUOUS 1-KB
    // record stores; block writes 57,344 B sequential. Chunked by 7 px
    // to bound live q registers. Lane mapping: sh = lane>>3 (head),
    // sc = (lane&7)*4 -> q reads are 8 x 128-B segments per instruction.
    const int sh = lane >> 3;
    const int sc = (lane & 7) * 4;
    const float* qh = q + (((size_t)b * NH + sh) * (size_t)NN + (size_t)y * HW) * CH + sc;
    float* orow = out + ((size_t)b * NN + (size_t)y * HW) * (NH * CH);

#pragma unroll
    for (int half = 0; half < 2; ++half) {
        f32x4 q4[7];
#pragma unroll
        for (int m = 0; m < 7; ++m) {
            const int px = (half * 7 + m) * 4 + wid;
            q4[m] = *(const f32x4*)(qh + (size_t)px * CH);
        }
#pragma unroll
        for (int m = 0; m < 7; ++m) {
            const int px = (half * 7 + m) * 4 + wid;
            const f32x4 c4 = *(const f32x4*)(outL + (size_t)px * OUTROWF + lane * 4);
            *(f32x4*)(orow + (size_t)px * (NH * CH) + lane * 4) = c4 * q4[m];
        }
    }
}

extern "C" void kernel_launch(void* const* d_in, const int* in_sizes, int n_in,
                              void* d_out, int out_size, void* d_ws, size_t ws_size,
                              hipStream_t stream) {
    const float* q  = (const float*)d_in[0];
    const float* v  = (const float*)d_in[1];
    const float* w3 = (const float*)d_in[2];
    const float* b3 = (const float*)d_in[3];
    const float* w5 = (const float*)d_in[4];
    const float* b5 = (const float*)d_in[5];
    const float* w7 = (const float*)d_in[6];
    const float* b7 = (const float*)d_in[7];
    float* out = (float*)d_out;

    const int grid = BH * HW;          // 896 blocks of 256 threads
    clusterformer_fused<<<grid, 256, 0, stream>>>(q, v, w3, b3, w5, b5, w7, b7, out);
}

// Round 12
// 163.692 us; speedup vs baseline: 2.2235x; 1.0981x over previous
//
#include <hip/hip_runtime.h>
#include <cstddef>

// B=16, h=8, Ch=32, H=W=56, N=3136
//   heads 0-1 -> 3x3 (w3,b3), cbase hh*32
//   heads 2-4 -> 5x5 (w5,b5), cbase hh*32-64
//   heads 5-7 -> 7x7 (w7,b7), cbase hh*32-160
// out[b][n][hh*32+ch] = q[b][hh][n][ch] * dwconv(v)[b][hh][n][ch]
//
// R17: RESTORATION of the best-measured kernel (R10; 52.3-53.1 us/dispatch,
// bench 161.75 us). R16 (write-granule test, clean) regressed to 68.7 us
// and completed the falsification matrix:
//   occupancy(R6) / LDS-roundtrip(R7) / redundancy(R8) / issue-volume(R9)
//   / write-L2-coresidency(R10) / phase-overlap(R11) / L2-workingset(R12)
//   / write-granularity(R16) -- all null or negative.
// Key evidence: L3-warm dispatches show HALF the HBM bytes at identical
// 53 us => HBM traffic is not the binder; VALU 13%, LDS 0-conflict, L2
// ~3/34 TB/s. The ~53 us floor is invariant to every source-level lever.
// Structure (R9/R10): lane owns 3-4 output rows (each staged row ds_read
// ONCE, lowest issue volume of the series); block stages 14+2P rows once
// (149 KB LDS, 1 block/CU); all-8-heads-of-a-slab co-scheduled per XCD.

#define BH 16
#define NH 8
#define CH 32
#define HW 56
#define NN (HW*HW)
#define ROWB (HW*CH*4)          // 7168 B per image row
#define RS 58                   // LDS row stride in px (56 + 2 gap)
#define NROWS_MAX 20            // 14 + 2*3 (K=7)
#define BUF_PX (3 + NROWS_MAX*RS + 1)   // 1164 px
#define BUF_FLOATS (BUF_PX*CH)  // 37248 floats = 148992 B

typedef float f32x4 __attribute__((ext_vector_type(4)));
typedef unsigned int u32x4 __attribute__((ext_vector_type(4)));

__device__ __forceinline__ f32x4 bload(__amdgpu_buffer_rsrc_t rs, int voff) {
    u32x4 u = __builtin_amdgcn_raw_buffer_load_b128(rs, voff, 0, 0);
    f32x4 f; __builtin_memcpy(&f, &u, 16); return f;
}

// One wave computes R consecutive output rows (y0+sw .. y0+sw+R-1).
// Input staged rows s = sw+rr, rr in [0, R+2P): read window ONCE, apply to
// every output row u with dy = rr - u in [0,K).
template<int K, int R>
__device__ __forceinline__ void conv_rows(
    const float* __restrict__ q, float* __restrict__ out,
    const float* __restrict__ bias,
    int b, int hh, int y0, int sw, int cbase,
    const float* __restrict__ w_lds, const float* __restrict__ bufs,
    int lane)
{
    constexpr int P  = K / 2;
    constexpr int NR = 7 + K - 1;       // window px per 7-px strip
    const int xseg = lane >> 3;         // 8 x-strips of 7 px
    const int chq  = lane & 7;          // 8 ch-quads
    const int x0   = xseg * 7;
    const int ch   = chq * 4;

    // K=7 edge masks: window px -3/+58 land on neighbor-row data (not gap).
    const float mL = (xseg == 0) ? 0.f : 1.f;
    const float mR = (xseg == 7) ? 0.f : 1.f;

    const f32x4 bias4 = *(const f32x4*)(bias + cbase + ch);
    f32x4 acc[R][7];
#pragma unroll
    for (int u = 0; u < R; ++u)
#pragma unroll
        for (int i = 0; i < 7; ++i) acc[u][i] = bias4;

    // rr loop kept RUNTIME (not unrolled): bounds icache, guards below are
    // wave-uniform scalar branches.
    for (int rr = 0; rr < R + 2 * P; ++rr) {
        const float* rb = bufs + (size_t)((3 - P + x0) + (sw + rr) * RS) * CH + ch;
        f32x4 r[NR];
#pragma unroll
        for (int j = 0; j < NR; ++j)
            r[j] = *(const f32x4*)(rb + j * CH);
        if constexpr (K == 7) { r[0] *= mL; r[NR - 1] *= mR; }

#pragma unroll
        for (int u = 0; u < R; ++u) {
            const int dy = rr - u;
            if ((unsigned)dy < (unsigned)K) {
#pragma unroll
                for (int dx = 0; dx < K; ++dx) {
                    const f32x4 w4 = *(const f32x4*)(w_lds + (dy * K + dx) * CH + ch);
#pragma unroll
                    for (int i = 0; i < 7; ++i)
                        acc[u][i] += r[i + dx] * w4;
                }
            }
        }
    }

    // Epilogue per row: q load, multiply, plain store (dirty lines linger
    // in L2 so the 8 co-scheduled heads assemble full 1-KB records).
    const size_t plane = ((size_t)b * NH + hh) * (size_t)NN * CH;
#pragma unroll
    for (int u = 0; u < R; ++u) {
        const int y = y0 + sw + u;
        const float* qrow = q + plane + (size_t)y * (HW * CH);
        float* obase = out + ((size_t)b * NN + (size_t)y * HW) * (NH * CH) + hh * CH + ch;
#pragma unroll
        for (int i = 0; i < 7; ++i) {
            const int px = x0 + i;
            const f32x4 q4 = *(const f32x4*)(qrow + (size_t)px * CH + ch);
            *(f32x4*)(obase + (size_t)px * (NH * CH)) = acc[u][i] * q4;
        }
    }
}

template<int K>
__device__ __forceinline__ void run_head(
    const float* __restrict__ q, const float* __restrict__ v,
    const float* __restrict__ w, const float* __restrict__ bias,
    float* __restrict__ out, int b, int hh, int y0, int cbase,
    float* __restrict__ w_lds, float* __restrict__ bufs)
{
    constexpr int P = K / 2;
    constexpr int NROWS = 14 + 2 * P;   // staged rows per block
    constexpr int NS = (NROWS + 3) / 4; // staged rows per wave (max)
    const int t = threadIdx.x;

    // Stage weights into LDS, layout [tap][c].
    const int nw = K * K * CH;
    for (int i = t; i < nw; i += 256) {
        int tap = i >> 5, c = i & 31;
        w_lds[tap * CH + c] = w[(cbase + c) * (K * K) + tap];
    }

    // Zero pad px: lead 3, 2-px gap after each row, 1 trailing.
    {
        f32x4 z = {0.f, 0.f, 0.f, 0.f};
        const int NG = 3 + 2 * NROWS + 1;
        for (int i = t; i < NG * 8; i += 256) {
            const int g = i >> 3, sub = i & 7;
            int px;
            if (g < 3) px = g;
            else if (g < 3 + 2 * NROWS) {
                const int s = (g - 3) >> 1;
                px = 3 + s * RS + 56 + ((g - 3) & 1);
            } else px = 3 + NROWS * RS;
            *(f32x4*)(bufs + (size_t)px * CH + sub * 4) = z;
        }
    }

    const int wid  = t >> 6;
    const int lane = t & 63;
    const size_t plane = ((size_t)b * NH + hh) * (size_t)NN * CH;
    const float* vb = v + plane;

    // Cooperative staging: wave wid stages rows wid, wid+4, ... All loads
    // issued first (ld[] register-resident, static indexing), then writes.
    // OOB rows: num_records=0 -> zeros = y zero-padding (proven R2-R4).
    f32x4 ld[NS][7];
#pragma unroll
    for (int n = 0; n < NS; ++n) {
        const int s = wid + n * 4;
        if (s < NROWS) {
            const int gy = y0 - P + s;
            const bool ok = (unsigned)gy < (unsigned)HW;
            __amdgpu_buffer_rsrc_t rs = __builtin_amdgcn_make_buffer_rsrc(
                (void*)(vb + (ptrdiff_t)gy * (HW * CH)), (short)0, ok ? ROWB : 0, 0x00020000);
#pragma unroll
            for (int k = 0; k < 7; ++k) ld[n][k] = bload(rs, k * 1024 + lane * 16);
        }
    }
#pragma unroll
    for (int n = 0; n < NS; ++n) {
        const int s = wid + n * 4;
        if (s < NROWS) {
            float* dst = bufs + (size_t)(3 + s * RS) * CH;
#pragma unroll
            for (int k = 0; k < 7; ++k)
                *(f32x4*)(dst + k * 256 + lane * 4) = ld[n][k];
        }
    }
    __syncthreads();                    // only barrier in the kernel

    // Row split {4,3,3,4} over 14 rows; waves exit independently after.
    if      (wid == 0) conv_rows<K, 4>(q, out, bias, b, hh, y0, 0,  cbase, w_lds, bufs, lane);
    else if (wid == 1) conv_rows<K, 3>(q, out, bias, b, hh, y0, 4,  cbase, w_lds, bufs, lane);
    else if (wid == 2) conv_rows<K, 3>(q, out, bias, b, hh, y0, 7,  cbase, w_lds, bufs, lane);
    else               conv_rows<K, 4>(q, out, bias, b, hh, y0, 10, cbase, w_lds, bufs, lane);
}

__global__ __launch_bounds__(256, 1)   // 155.3 KB LDS -> 1 block/CU
void clusterformer_fused(const float* __restrict__ q, const float* __restrict__ v,
                         const float* __restrict__ w3, const float* __restrict__ b3,
                         const float* __restrict__ w5, const float* __restrict__ b5,
                         const float* __restrict__ w7, const float* __restrict__ b7,
                         float* __restrict__ out)
{
    __shared__ __align__(16) float bufs[BUF_FLOATS];   // 148992 B
    __shared__ __align__(16) float w_lds[49 * CH];     // 6272 B

    // bid -> (xcd, slot): slot enumerates (yg, b_hi, head) with HEAD the
    // fastest-varying field. All 8 head-blocks of one (b, y-slab) occupy 8
    // consecutive slots on ONE XCD -> run concurrently, assemble complete
    // out records in that XCD's L2. b&7 == xcd keeps q/v planes XCD-local.
    const int bid  = blockIdx.x;
    const int xcd  = bid & 7;
    const int slot = bid >> 3;         // 0..63 within XCD
    const int hhp  = slot & 7;         // head, fastest
    const int t2   = slot >> 3;        // 0..7
    const int b    = ((t2 & 1) << 3) | xcd;
    const int yg   = t2 >> 1;          // 0..3
    const int hh   = (hhp < 3) ? (5 + hhp) : ((hhp < 6) ? (hhp - 1) : (hhp - 6));
    const int y0   = yg * 14;

    if (hh < 2)      run_head<3>(q, v, w3, b3, out, b, hh, y0, hh * 32,       w_lds, bufs);
    else if (hh < 5) run_head<5>(q, v, w5, b5, out, b, hh, y0, hh * 32 - 64,  w_lds, bufs);
    else             run_head<7>(q, v, w7, b7, out, b, hh, y0, hh * 32 - 160, w_lds, bufs);
}

extern "C" void kernel_launch(void* const* d_in, const int* in_sizes, int n_in,
                              void* d_out, int out_size, void* d_ws, size_t ws_size,
                              hipStream_t stream) {
    const float* q  = (const float*)d_in[0];
    const float* v  = (const float*)d_in[1];
    const float* w3 = (const float*)d_in[2];
    const float* b3 = (const float*)d_in[3];
    const float* w5 = (const float*)d_in[4];
    const float* b5 = (const float*)d_in[5];
    const float* w7 = (const float*)d_in[6];
    const float* b7 = (const float*)d_in[7];
    float* out = (float*)d_out;

    const int grid = BH * NH * 4;      // 512 blocks of 256 threads
    clusterformer_fused<<<grid, 256, 0, stream>>>(q, v, w3, b3, w5, b5, w7, b7, out);
}